// Round 4
// baseline (95.283 us; speedup 1.0000x reference)
//
#include <hip/hip_runtime.h>

#define T_LEN 256
#define NG 24              // 24 groups x 16 steps = 384 steps (need s_max = 382)

__device__ __forceinline__ float ex2(float x) { return __builtin_amdgcn_exp2f(x); }
__device__ __forceinline__ float rcpf_(float x) { return __builtin_amdgcn_rcpf(x); }

// Shift-with-fill: lane i <- lane i-1 (wave_shr:1, 0x138); lane 0 (sourceless,
// bound_ctrl=false) keeps OLD = fill. One instruction on the chain.
__device__ __forceinline__ float dpp_shr1_fill(float fill, float v) {
    int f = __float_as_int(fill), i = __float_as_int(v);
    return __int_as_float(__builtin_amdgcn_update_dpp(f, i, 0x138, 0xF, 0xF, false));
}
// Shift-with-fill the other way: lane i <- lane i+1 (wave_shl:1, 0x130);
// lane 63 (sourceless) keeps OLD = fill. Fuses the conveyor rotate+inject.
__device__ __forceinline__ float dpp_shl1_fill(float fill, float v) {
    int f = __float_as_int(fill), i = __float_as_int(v);
    return __int_as_float(__builtin_amdgcn_update_dpp(f, i, 0x130, 0xF, 0xF, false));
}
// Full rotate: lane i <- lane (i-1)&63 (wave_ror:1, 0x13C); lane 0 <- lane 63.
// Rotate counterpart of the HW-verified wave_shr:1 above (same direction).
__device__ __forceinline__ float dpp_ror1(float v) {
    int i = __float_as_int(v);
    return __int_as_float(__builtin_amdgcn_update_dpp(i, i, 0x13C, 0xF, 0xF, false));
}

// R22: SINGLE-WAVE restructure (cell math = proven R18 body, verbatim).
// 64 lanes; lane i owns TWO layers: A = layer i, B = layer 64+i. Two
// independent interleaved dependence chains per step (no intra-step dep
// between A and B on the same lane).
//   schedule: cell A(i,t) at step s = t + i     (identical to old wave0)
//             cell B(i,t) at step s = t + 64 + i
//   seam: B(0,t) needs A(63,t) = hA(lane63) finished at step t+63, consumed
//         at step t+64: rA = dpp_ror1(hA) BEFORE this step's hA update gives
//         lane0 exactly A(63, s-64). One-step in-register seam — replaces the
//         17-step LDS ring of the 2-wave design.
// Removes vs R18/R21: all 25 __syncthreads (single wave => none needed after
// init), the LDS ring + per-group dump + 16 ring reads (and their ~120cy
// group-head lgkm stall), and 16 seam-delay steps (400 -> 384 steps; the
// diagonal lower bound is 383).
// Freeze semantics unchanged: Ez := 0 when cell not yet born => h' = h
// exactly (h==0 pre-birth stays 0). Ramp-out garbage is FINITE here (|h|
// bounded by the z/n hull, no stale ring reads) and only ever feeds dead
// cells: lane0-A goes dead at s=256 exactly when its successors are dead;
// last live seam consume is B(0,255) at s=319 reading A(63,255) from s=318.
// Output: out[t] = B(63,t) = hB(lane63) at end of step t+127. Conveyor
// ov = dpp_shl1_fill(hB, ov) (lane63 injects, values shift down); after 64
// injections lanes 0..63 hold 64 consecutive t: coalesced stores at
// s = 190,254,318,382  (k==14; g = 11,15,19,23), out[16g-176+lane].
__global__ __launch_bounds__(64, 1) void gru_stack_wavefront(
    const float* __restrict__ x,
    const float* __restrict__ w_ih,
    const float* __restrict__ w_hh,
    const float* __restrict__ b_ih,
    const float* __restrict__ b_hh,
    float* __restrict__ out)
{
    __shared__ float sx[T_LEN];
    const int lane = threadIdx.x;         // 0..63

    sx[lane]       = x[lane];
    sx[lane + 64]  = x[lane + 64];
    sx[lane + 128] = x[lane + 128];
    sx[lane + 192] = x[lane + 192];

    const float L1 = -1.4426950408889634f;   // -log2(e)
    const float L2 = -2.8853900817779268f;   // -2*log2(e)

    const int la = lane;                  // layer A index
    const int lb = lane + 64;             // layer B index

    const float wi_rA = L1 * w_ih[3 * la + 0], wh_rA = L1 * w_hh[3 * la + 0];
    const float b_rA  = L1 * (b_ih[3 * la + 0] + b_hh[3 * la + 0]);
    const float wi_zA = L1 * w_ih[3 * la + 1], wh_zA = L1 * w_hh[3 * la + 1];
    const float b_zA  = L1 * (b_ih[3 * la + 1] + b_hh[3 * la + 1]);
    const float wi_nA = L2 * w_ih[3 * la + 2], bi_nA = L2 * b_ih[3 * la + 2];
    const float wh_nA = L2 * w_hh[3 * la + 2], bh_nA = L2 * b_hh[3 * la + 2];

    const float wi_rB = L1 * w_ih[3 * lb + 0], wh_rB = L1 * w_hh[3 * lb + 0];
    const float b_rB  = L1 * (b_ih[3 * lb + 0] + b_hh[3 * lb + 0]);
    const float wi_zB = L1 * w_ih[3 * lb + 1], wh_zB = L1 * w_hh[3 * lb + 1];
    const float b_zB  = L1 * (b_ih[3 * lb + 1] + b_hh[3 * lb + 1]);
    const float wi_nB = L2 * w_ih[3 * lb + 2], bi_nB = L2 * b_ih[3 * lb + 2];
    const float wh_nB = L2 * w_hh[3 * lb + 2], bh_nB = L2 * b_hh[3 * lb + 2];

    float hA = 0.0f, hB = 0.0f;
    float c_rA = b_rA, c_zA = b_zA, g_nA = bh_nA;
    float c_rB = b_rB, c_zB = b_zB, g_nB = bh_nB;

    float pk[16];
    #pragma unroll
    for (int k = 0; k < 16; ++k) pk[k] = 0.0f;

    float ov = 0.0f;                      // output conveyor (hB, lane63 injects)

    __syncthreads();                      // sx init visible (single wave: cheap)

    // ---------- ramp loop: g = 0..7 (s = 0..127), freeze active ----------
    // A born at s=i (<=63), B born at s=64+i (<=127): from s=128 all live.
    for (int g = 0; g < 8; ++g) {
        #pragma unroll
        for (int k = 0; k < 16; ++k)
            pk[k] = sx[16 * g + k];                      // x[s], s <= 127

        #pragma unroll
        for (int k = 0; k < 16; ++k) {
            const int s = 16 * g + k;
            const bool validA = (unsigned)(s - lane) < (unsigned)T_LEN;
            const bool validB = (unsigned)(s - 64 - lane) < (unsigned)T_LEN;

            // capture prev-step states before any update
            float rA  = dpp_ror1(hA);                    // lane0: A(63, s-64)
            float inA = dpp_shr1_fill(pk[k], hA);        // lane0: x[s]
            float inB = dpp_shr1_fill(rA, hB);           // lane0: seam value

            // ---- cell A (proven R18 body) ----
            float u_rA  = fmaf(wi_rA, inA, c_rA);
            float u_zA  = fmaf(wi_zA, inA, c_zA);
            float u_n0A = fmaf(wi_nA, inA, bi_nA);
            float rrA = rcpf_(1.0f + ex2(u_rA));
            float EzA = ex2(u_zA);
            EzA = validA ? EzA : 0.0f;                   // freeze: h' = h
            float EnA = ex2(fmaf(rrA, g_nA, u_n0A));
            float t1A  = 1.0f + EnA;
            float denA = fmaf(EzA, t1A, t1A);
            float bbA  = fmaf(-EzA, EnA, EzA);
            float numA = fmaf(hA, t1A, bbA);
            hA = numA * rcpf_(denA);
            c_rA = fmaf(wh_rA, hA, b_rA);
            c_zA = fmaf(wh_zA, hA, b_zA);
            g_nA = fmaf(wh_nA, hA, bh_nA);

            // ---- cell B (independent chain) ----
            float u_rB  = fmaf(wi_rB, inB, c_rB);
            float u_zB  = fmaf(wi_zB, inB, c_zB);
            float u_n0B = fmaf(wi_nB, inB, bi_nB);
            float rrB = rcpf_(1.0f + ex2(u_rB));
            float EzB = ex2(u_zB);
            EzB = validB ? EzB : 0.0f;                   // freeze: h' = h
            float EnB = ex2(fmaf(rrB, g_nB, u_n0B));
            float t1B  = 1.0f + EnB;
            float denB = fmaf(EzB, t1B, t1B);
            float bbB  = fmaf(-EzB, EnB, EzB);
            float numB = fmaf(hB, t1B, bbB);
            hB = numB * rcpf_(denB);
            c_rB = fmaf(wh_rB, hB, b_rB);
            c_zB = fmaf(wh_zB, hB, b_zB);
            g_nB = fmaf(wh_nB, hB, bh_nB);

            ov = dpp_shl1_fill(hB, ov);                  // inject + rotate
        }
    }

    // ---------- steady loop: g = 8..23, freeze-free (dead-lane values
    // finite and only ever consumed by dead cells — see header) ----------
    for (int g = 8; g < NG; ++g) {
        #pragma unroll
        for (int k = 0; k < 16; ++k)
            pk[k] = sx[(16 * g + k) & (T_LEN - 1)];      // wrap: dead lane0 only

        #pragma unroll
        for (int k = 0; k < 16; ++k) {
            float rA  = dpp_ror1(hA);                    // lane0: A(63, s-64)
            float inA = dpp_shr1_fill(pk[k], hA);        // lane0: x[s]
            float inB = dpp_shr1_fill(rA, hB);           // lane0: seam value

            // ---- cell A ----
            float u_rA  = fmaf(wi_rA, inA, c_rA);
            float u_zA  = fmaf(wi_zA, inA, c_zA);
            float u_n0A = fmaf(wi_nA, inA, bi_nA);
            float rrA = rcpf_(1.0f + ex2(u_rA));
            float EzA = ex2(u_zA);
            float EnA = ex2(fmaf(rrA, g_nA, u_n0A));
            float t1A  = 1.0f + EnA;
            float denA = fmaf(EzA, t1A, t1A);
            float bbA  = fmaf(-EzA, EnA, EzA);
            float numA = fmaf(hA, t1A, bbA);
            hA = numA * rcpf_(denA);
            c_rA = fmaf(wh_rA, hA, b_rA);
            c_zA = fmaf(wh_zA, hA, b_zA);
            g_nA = fmaf(wh_nA, hA, bh_nA);

            // ---- cell B ----
            float u_rB  = fmaf(wi_rB, inB, c_rB);
            float u_zB  = fmaf(wi_zB, inB, c_zB);
            float u_n0B = fmaf(wi_nB, inB, bi_nB);
            float rrB = rcpf_(1.0f + ex2(u_rB));
            float EzB = ex2(u_zB);
            float EnB = ex2(fmaf(rrB, g_nB, u_n0B));
            float t1B  = 1.0f + EnB;
            float denB = fmaf(EzB, t1B, t1B);
            float bbB  = fmaf(-EzB, EnB, EzB);
            float numB = fmaf(hB, t1B, bbB);
            hB = numB * rcpf_(denB);
            c_rB = fmaf(wh_rB, hB, b_rB);
            c_zB = fmaf(wh_zB, hB, b_zB);
            g_nB = fmaf(wh_nB, hB, bh_nB);

            ov = dpp_shl1_fill(hB, ov);                  // inject + rotate

            if (k == 14) {                               // s = 190,254,318,382
                if ((g & 3) == 3 && g >= 11)
                    out[16 * g - 176 + lane] = ov;       // coalesced store
            }
        }
    }
}

extern "C" void kernel_launch(void* const* d_in, const int* in_sizes, int n_in,
                              void* d_out, int out_size, void* d_ws, size_t ws_size,
                              hipStream_t stream) {
    const float* x    = (const float*)d_in[0];  // [1,256]
    const float* w_ih = (const float*)d_in[1];  // [128,3,1]
    const float* w_hh = (const float*)d_in[2];  // [128,3,1]
    const float* b_ih = (const float*)d_in[3];  // [128,3]
    const float* b_hh = (const float*)d_in[4];  // [128,3]
    float* out = (float*)d_out;                 // [1,256]

    gru_stack_wavefront<<<1, 64, 0, stream>>>(x, w_ih, w_hh, b_ih, b_hh, out);
}

// Round 5
// 84.442 us; speedup vs baseline: 1.1284x; 1.1284x over previous
//
#include <hip/hip_runtime.h>

#define T_LEN 256
#define NG 25              // 25 groups x 16 steps = 400 steps (need s_max = 398)

__device__ __forceinline__ float ex2(float x) { return __builtin_amdgcn_exp2f(x); }
__device__ __forceinline__ float rcpf_(float x) { return __builtin_amdgcn_rcpf(x); }

// Shift-with-fill: lane i <- lane i-1 (wave_shr:1, 0x138); lane 0 (sourceless,
// bound_ctrl=false) keeps OLD = fill. One instruction on the chain.
__device__ __forceinline__ float dpp_shr1_fill(float fill, float v) {
    int f = __float_as_int(fill), i = __float_as_int(v);
    return __int_as_float(__builtin_amdgcn_update_dpp(f, i, 0x138, 0xF, 0xF, false));
}
// Shift-with-fill the other way: lane i <- lane i+1 (wave_shl:1, 0x130);
// lane 63 (sourceless) keeps OLD = fill. Fuses the conveyor rotate+inject.
__device__ __forceinline__ float dpp_shl1_fill(float fill, float v) {
    int f = __float_as_int(fill), i = __float_as_int(v);
    return __int_as_float(__builtin_amdgcn_update_dpp(f, i, 0x130, 0xF, 0xF, false));
}

// FINAL RESTORE of the proven optimum (R18 skeleton, round-0 source).
// Session evidence that this is the floor:
//  - R19 (sched bundle): +3.2us. R20 (den-fold only): +1.9us. R22 (single-
//    wave, 384 steps, no barriers/ring): +11.8us. All perturbations regress.
//  - Identical source reproduces within +-1us (83.48 / 84.43).
//  - Step count 400 vs 383 diagonal lower bound (+4%); per-step time matches
//    the h->h' dependent chain (ex2->rcp->fma->ex2->add->fma->rcp->mul,
//    ~58-60cy) at the observed effective clock; the 2 waves already overlap
//    issue with each other's chain latency (proven by R22: halving waves
//    while doubling per-wave work cost +30% kernel time).
//  - Remaining dur_us is harness re-poison fill (39.5us @ 85% HBM peak)
//    + ~5us overhead + ~39us kernel pinned at the dependence chain.
//   z = 1/(1+E_z), n = (1-E_n)/(1+E_n)  (E_z = exp2(u_z'), E_n = exp2(un'))
//   h' = (1-z)n + zh = [E_z(1-E_n) + h(1+E_n)] / [(1+E_n)(1+E_z)]
// -> ONE rcp (of the product) replaces the two tail rcps: 5 transcendentals
// per step instead of 6; -1 add; +1 mul. Freeze ports exactly as E_z := 0
// (=> num = h*t1, den = t1, h' = h*t1*rcp(t1); ramp-in h==0 stays 0 EXACTLY).
// Ramp-out inf/NaN in dead lanes is contained: valid consumers only read
// valid-produced values (R18 proof); ring/conveyor garbage feeds only
// invalid cells whose outputs are never consumed.
// TWO waves, 1 layer/lane. cell (l,t) at step s = t + l + 16*(l>=64).
//  - step-head input: in = dpp(old=pk[k], src=h, wave_shr:1)  (R17).
//  - output conveyor fused: ov = dpp(old=h, src=ov, wave_shl:1) (R18).
//  - ramp loop g=0..8 (freeze), steady loop g=9..24 (freeze-free) (R18).
//  - seam ring: per-GROUP conveyor dump; reads barrier-covered, races
//    disjoint-or-identical, overwrite >=2 barriers away (R16 proof).
//  - out: coalesced 64-lane stores at s=206,270,334,398 (k==14, g=12,16,20,24).
__global__ __launch_bounds__(128, 1) void gru_stack_wavefront(
    const float* __restrict__ x,
    const float* __restrict__ w_ih,
    const float* __restrict__ w_hh,
    const float* __restrict__ b_ih,
    const float* __restrict__ b_hh,
    float* __restrict__ out)
{
    __shared__ float ring[2 * 64];        // [wid][slot]: h(63) / h(127) history
    __shared__ float sx[T_LEN];
    const int tid  = threadIdx.x;         // 0..127 == layer index
    const int lane = tid & 63;
    const int wid  = tid >> 6;

    ring[tid] = 0.0f;                     // zero-init both planes
    sx[tid] = x[tid];
    sx[tid + 128] = x[tid + 128];

    const float L1 = -1.4426950408889634f;   // -log2(e)
    const float L2 = -2.8853900817779268f;   // -2*log2(e)

    const float wi_r = L1 * w_ih[3 * tid + 0], wh_r = L1 * w_hh[3 * tid + 0];
    const float b_r  = L1 * (b_ih[3 * tid + 0] + b_hh[3 * tid + 0]);
    const float wi_z = L1 * w_ih[3 * tid + 1], wh_z = L1 * w_hh[3 * tid + 1];
    const float b_z  = L1 * (b_ih[3 * tid + 1] + b_hh[3 * tid + 1]);
    const float wi_n = L2 * w_ih[3 * tid + 2], bi_n = L2 * b_ih[3 * tid + 2];
    const float wh_n = L2 * w_hh[3 * tid + 2], bh_n = L2 * b_hh[3 * tid + 2];

    float h = 0.0f;
    float c_r = b_r, c_z = b_z, g_n = bh_n;

    float pk[16];
    #pragma unroll
    for (int k = 0; k < 16; ++k) pk[k] = 0.0f;

    float ov = 0.0f;                      // conveyor: w0 feeds seam dump, w1 out
    int t = -lane - 80 * wid - 1;         // ++ at step top (ramp loop only)

    const bool is_w1 = (wid == 1);
    float* ringw = &ring[wid * 64];       // own plane (w1's never read)

    __syncthreads();                      // ring + sx init visible

    // ---------- ramp loop: g = 0..8 (s = 0..143), freeze active ----------
    for (int g = 0; g < 9; ++g) {
        if (is_w1) {
            const int base = 16 * g - 17;
            #pragma unroll
            for (int k = 0; k < 16; ++k)
                pk[k] = ring[(base + k) & 63];           // h(63, s-17)
        } else {
            #pragma unroll
            for (int k = 0; k < 16; ++k)
                pk[k] = sx[16 * g + k];                  // x[s], s <= 143
        }

        #pragma unroll
        for (int k = 0; k < 16; ++k) {
            ++t;
            const bool valid = (unsigned)t < (unsigned)T_LEN;

            float in = dpp_shr1_fill(pk[k], h);          // one-instr input path

            float u_r  = fmaf(wi_r, in, c_r);
            float u_z  = fmaf(wi_z, in, c_z);
            float u_n0 = fmaf(wi_n, in, bi_n);
            float r  = rcpf_(1.0f + ex2(u_r));
            float Ez = ex2(u_z);
            Ez = valid ? Ez : 0.0f;                      // freeze: h' = h (exact at h=0)
            float En = ex2(fmaf(r, g_n, u_n0));
            float t1  = 1.0f + En;                       // (1+E_n)
            float den = fmaf(Ez, t1, t1);                // (1+E_n)(1+E_z)
            float bb  = fmaf(-Ez, En, Ez);               // E_z(1-E_n), off-chain
            float num = fmaf(h, t1, bb);                 // h(1+E_n) + E_z(1-E_n)
            h = num * rcpf_(den);

            c_r = fmaf(wh_r, h, b_r);
            c_z = fmaf(wh_z, h, b_z);
            g_n = fmaf(wh_n, h, bh_n);

            ov = dpp_shl1_fill(h, ov);                   // fused rotate+inject
        }
        ringw[(16 * g + 16 + lane) & 63] = ov;           // group-end dump
        __syncthreads();
    }

    // ---------- steady loop: g = 9..24, freeze-free (ramp-out garbage
    // provably never consumed; NaN contained — see header) ----------
    for (int g = 9; g < NG; ++g) {
        if (is_w1) {
            const int base = 16 * g - 17;
            #pragma unroll
            for (int k = 0; k < 16; ++k)
                pk[k] = ring[(base + k) & 63];           // h(63, s-17)
        } else {
            #pragma unroll
            for (int k = 0; k < 16; ++k)
                pk[k] = sx[(16 * g + k) & (T_LEN - 1)];  // x[s] (wrap: dead lanes)
        }

        #pragma unroll
        for (int k = 0; k < 16; ++k) {
            float in = dpp_shr1_fill(pk[k], h);          // one-instr input path

            float u_r  = fmaf(wi_r, in, c_r);
            float u_z  = fmaf(wi_z, in, c_z);
            float u_n0 = fmaf(wi_n, in, bi_n);
            float r  = rcpf_(1.0f + ex2(u_r));
            float Ez = ex2(u_z);
            float En = ex2(fmaf(r, g_n, u_n0));
            float t1  = 1.0f + En;
            float den = fmaf(Ez, t1, t1);
            float bb  = fmaf(-Ez, En, Ez);
            float num = fmaf(h, t1, bb);
            h = num * rcpf_(den);

            c_r = fmaf(wh_r, h, b_r);
            c_z = fmaf(wh_z, h, b_z);
            g_n = fmaf(wh_n, h, bh_n);

            ov = dpp_shl1_fill(h, ov);                   // fused rotate+inject

            if (k == 14) {                               // s = 206,270,334,398
                if (is_w1 && (g & 3) == 0 && g >= 12)
                    out[16 * g - 192 + lane] = ov;       // coalesced store
            }
        }
        ringw[(16 * g + 16 + lane) & 63] = ov;           // group-end dump
        __syncthreads();
    }
}

extern "C" void kernel_launch(void* const* d_in, const int* in_sizes, int n_in,
                              void* d_out, int out_size, void* d_ws, size_t ws_size,
                              hipStream_t stream) {
    const float* x    = (const float*)d_in[0];  // [1,256]
    const float* w_ih = (const float*)d_in[1];  // [128,3,1]
    const float* w_hh = (const float*)d_in[2];  // [128,3,1]
    const float* b_ih = (const float*)d_in[3];  // [128,3]
    const float* b_hh = (const float*)d_in[4];  // [128,3]
    float* out = (float*)d_out;                 // [1,256]

    gru_stack_wavefront<<<1, 128, 0, stream>>>(x, w_ih, w_hh, b_ih, b_hh, out);
}